// Round 1
// baseline (1058.230 us; speedup 1.0000x reference)
//
#include <hip/hip_runtime.h>
#include <hip/hip_bf16.h>

#define B_  2
#define S_  2048
#define H_  1024
#define NH_ 16
#define HD_ 64

typedef __bf16 bf16_t;
typedef __attribute__((ext_vector_type(8))) __bf16 bf16x8;
typedef __attribute__((ext_vector_type(4))) float f32x4;

// ---------------------------------------------------------------------------
// Kernel 1: fused QKV projection. Y = X*W^T + b, cast to bf16, stored
// [B][NH][S][HD]. q additionally pre-scaled by 1/sqrt(HD)=0.125 (exact).
// 64x64 tile per block, 4 waves, mfma_f32_16x16x32_bf16.
// LDS rows padded to 72 bf16 (144B) -> <=2-way bank conflicts (free).
// ---------------------------------------------------------------------------
__global__ __launch_bounds__(256) void qkv_gemm(
    const float* __restrict__ X,
    const float* __restrict__ Wq, const float* __restrict__ bq,
    const float* __restrict__ Wk, const float* __restrict__ bk,
    const float* __restrict__ Wv, const float* __restrict__ bv,
    bf16_t* __restrict__ qbuf, bf16_t* __restrict__ kbuf, bf16_t* __restrict__ vbuf)
{
    const int which = blockIdx.z;
    const float* W    = which == 0 ? Wq : (which == 1 ? Wk : Wv);
    const float* bias = which == 0 ? bq : (which == 1 ? bk : bv);
    bf16_t* out       = which == 0 ? qbuf : (which == 1 ? kbuf : vbuf);
    const float scale = which == 0 ? 0.125f : 1.0f;

    const int m0 = blockIdx.x * 64;   // row block in [0,4096)
    const int n0 = blockIdx.y * 64;   // col block in [0,1024)
    const int t    = threadIdx.x;
    const int lane = t & 63;
    const int w    = t >> 6;          // wave 0..3
    const int lo   = lane & 15;
    const int g    = lane >> 4;       // quad 0..3

    __shared__ bf16_t Xs[64 * 72];
    __shared__ bf16_t Ws[64 * 72];

    f32x4 acc[4];
#pragma unroll
    for (int i = 0; i < 4; ++i) acc[i] = (f32x4){0.f, 0.f, 0.f, 0.f};

    for (int kc = 0; kc < 16; ++kc) {
        // stage X tile and W tile (fp32 global -> bf16 LDS)
#pragma unroll
        for (int p = 0; p < 4; ++p) {
            int idx = t + p * 256;          // 0..1023
            int row = idx >> 4;             // 0..63
            int c4  = (idx & 15) * 4;       // 0..60
            float4 xv = *(const float4*)&X[(size_t)(m0 + row) * H_ + kc * 64 + c4];
            bf16_t* xd = &Xs[row * 72 + c4];
            xd[0] = (bf16_t)xv.x; xd[1] = (bf16_t)xv.y;
            xd[2] = (bf16_t)xv.z; xd[3] = (bf16_t)xv.w;
            float4 wv = *(const float4*)&W[(size_t)(n0 + row) * H_ + kc * 64 + c4];
            bf16_t* wd = &Ws[row * 72 + c4];
            wd[0] = (bf16_t)wv.x; wd[1] = (bf16_t)wv.y;
            wd[2] = (bf16_t)wv.z; wd[3] = (bf16_t)wv.w;
        }
        __syncthreads();

        // A-frag: lane reads row (w*16+lo), k = g*8..g*8+7 (+32 for 2nd step)
        bf16x8 a0 = *(const bf16x8*)&Xs[(w * 16 + lo) * 72 + g * 8];
        bf16x8 a1 = *(const bf16x8*)&Xs[(w * 16 + lo) * 72 + g * 8 + 32];
#pragma unroll
        for (int nt = 0; nt < 4; ++nt) {
            bf16x8 b0 = *(const bf16x8*)&Ws[(nt * 16 + lo) * 72 + g * 8];
            bf16x8 b1 = *(const bf16x8*)&Ws[(nt * 16 + lo) * 72 + g * 8 + 32];
            acc[nt] = __builtin_amdgcn_mfma_f32_16x16x32_bf16(a0, b0, acc[nt], 0, 0, 0);
            acc[nt] = __builtin_amdgcn_mfma_f32_16x16x32_bf16(a1, b1, acc[nt], 0, 0, 0);
        }
        __syncthreads();
    }

    // epilogue: +bias, *scale, cast bf16, scatter to [B][NH][S][HD]
#pragma unroll
    for (int nt = 0; nt < 4; ++nt) {
        int n  = n0 + nt * 16 + lo;
        int hh = n >> 6, d = n & 63;
        float bv_ = bias[n];
#pragma unroll
        for (int r = 0; r < 4; ++r) {
            int m = m0 + w * 16 + g * 4 + r;     // C/D: row=(lane>>4)*4+reg
            int b = m >> 11, s = m & 2047;
            float val = (acc[nt][r] + bv_) * scale;
            out[(((size_t)(b * NH_ + hh) * S_) + s) * HD_ + d] = (bf16_t)val;
        }
    }
}

// ---------------------------------------------------------------------------
// Kernel 2: flash-style attention. One block per (b, h, 64-row q tile).
// 4 waves x 16 q-rows. K-chunks of 64. rel_pos/mask added in fp32.
// ---------------------------------------------------------------------------
__global__ __launch_bounds__(256) void attn(
    const bf16_t* __restrict__ qbuf, const bf16_t* __restrict__ kbuf,
    const bf16_t* __restrict__ vbuf,
    const float* __restrict__ mask, const float* __restrict__ rel,
    float* __restrict__ out)
{
    const int b = blockIdx.z, h = blockIdx.y, q0 = blockIdx.x * 64;
    const int t    = threadIdx.x;
    const int lane = t & 63;
    const int w    = t >> 6;
    const int lo   = lane & 15;
    const int g    = lane >> 4;

    __shared__ bf16_t Qs[64 * 72];
    __shared__ bf16_t Ks[64 * 72];
    __shared__ bf16_t VTs[64 * 72];      // V transposed: [d][s_local]
    __shared__ bf16_t Ps[4][16 * 72];    // per-wave P (C-layout -> A-layout)

    const bf16_t* qg = qbuf + ((size_t)(b * NH_ + h) * S_ + q0) * HD_;
    const bf16_t* kg = kbuf + (size_t)(b * NH_ + h) * S_ * HD_;
    const bf16_t* vg = vbuf + (size_t)(b * NH_ + h) * S_ * HD_;
    const float*  relg  = rel + ((size_t)((b * NH_ + h) * S_ + q0)) * S_;
    const float*  maskg = mask + b * S_;

    // stage Q tile (bf16 16B copies)
#pragma unroll
    for (int p = 0; p < 2; ++p) {
        int idx = t + p * 256;
        int row = idx >> 3, c8 = (idx & 7) * 8;
        *(uint4*)&Qs[row * 72 + c8] = *(const uint4*)&qg[row * 64 + c8];
    }
    __syncthreads();

    // Q A-frags for this wave's 16-row strip (held for whole kernel)
    bf16x8 aq0 = *(const bf16x8*)&Qs[(w * 16 + lo) * 72 + g * 8];
    bf16x8 aq1 = *(const bf16x8*)&Qs[(w * 16 + lo) * 72 + g * 8 + 32];

    float mi[4], li[4];
    f32x4 accO[4];
#pragma unroll
    for (int r = 0; r < 4; ++r) { mi[r] = -1e30f; li[r] = 0.f; }
#pragma unroll
    for (int dt = 0; dt < 4; ++dt) accO[dt] = (f32x4){0.f, 0.f, 0.f, 0.f};

    for (int kc = 0; kc < 32; ++kc) {
        // stage K (native) and V^T
#pragma unroll
        for (int p = 0; p < 2; ++p) {
            int idx = t + p * 256;
            int row = idx >> 3, c8 = (idx & 7) * 8;
            *(uint4*)&Ks[row * 72 + c8] = *(const uint4*)&kg[(size_t)(kc * 64 + row) * 64 + c8];
            uint4 vv = *(const uint4*)&vg[(size_t)(kc * 64 + row) * 64 + c8];
            const bf16_t* vvp = (const bf16_t*)&vv;
#pragma unroll
            for (int j = 0; j < 8; ++j) VTs[(c8 + j) * 72 + row] = vvp[j];
        }
        __syncthreads();

        // QK^T: 16x64 strip per wave (q pre-scaled by 1/8)
        f32x4 sc[4];
#pragma unroll
        for (int nt = 0; nt < 4; ++nt) {
            bf16x8 b0 = *(const bf16x8*)&Ks[(nt * 16 + lo) * 72 + g * 8];
            bf16x8 b1 = *(const bf16x8*)&Ks[(nt * 16 + lo) * 72 + g * 8 + 32];
            f32x4 z = (f32x4){0.f, 0.f, 0.f, 0.f};
            z = __builtin_amdgcn_mfma_f32_16x16x32_bf16(aq0, b0, z, 0, 0, 0);
            z = __builtin_amdgcn_mfma_f32_16x16x32_bf16(aq1, b1, z, 0, 0, 0);
            sc[nt] = z;
        }

        // + mask + rel_pos (fp32), into sv[r][nt]
        float sv[4][4];
#pragma unroll
        for (int nt = 0; nt < 4; ++nt) {
            float mk = maskg[kc * 64 + nt * 16 + lo];
#pragma unroll
            for (int r = 0; r < 4; ++r) {
                int row = w * 16 + g * 4 + r;
                sv[r][nt] = sc[nt][r] + mk +
                            relg[(size_t)row * S_ + kc * 64 + nt * 16 + lo];
            }
        }

        // online softmax per row; write P (bf16) into per-wave LDS
#pragma unroll
        for (int r = 0; r < 4; ++r) {
            float vmax = fmaxf(fmaxf(sv[r][0], sv[r][1]), fmaxf(sv[r][2], sv[r][3]));
#pragma unroll
            for (int mk = 1; mk < 16; mk <<= 1)
                vmax = fmaxf(vmax, __shfl_xor(vmax, mk, 16));
            float mnew  = fmaxf(mi[r], vmax);
            float alpha = __expf(mi[r] - mnew);
            float rsum = 0.f;
#pragma unroll
            for (int nt = 0; nt < 4; ++nt) {
                float p = __expf(sv[r][nt] - mnew);
                sv[r][nt] = p;
                rsum += p;
            }
#pragma unroll
            for (int mk = 1; mk < 16; mk <<= 1)
                rsum += __shfl_xor(rsum, mk, 16);
            li[r] = li[r] * alpha + rsum;
            mi[r] = mnew;
#pragma unroll
            for (int dt = 0; dt < 4; ++dt) accO[dt][r] *= alpha;
#pragma unroll
            for (int nt = 0; nt < 4; ++nt)
                Ps[w][(g * 4 + r) * 72 + nt * 16 + lo] = (bf16_t)sv[r][nt];
        }
        __syncthreads();   // P visible; also fences before VT reads below

        // PV: P(16 x 64) * V(64 x 64chunk)
        bf16x8 pa0 = *(const bf16x8*)&Ps[w][lo * 72 + g * 8];
        bf16x8 pa1 = *(const bf16x8*)&Ps[w][lo * 72 + g * 8 + 32];
#pragma unroll
        for (int dt = 0; dt < 4; ++dt) {
            bf16x8 v0 = *(const bf16x8*)&VTs[(dt * 16 + lo) * 72 + g * 8];
            bf16x8 v1 = *(const bf16x8*)&VTs[(dt * 16 + lo) * 72 + g * 8 + 32];
            accO[dt] = __builtin_amdgcn_mfma_f32_16x16x32_bf16(pa0, v0, accO[dt], 0, 0, 0);
            accO[dt] = __builtin_amdgcn_mfma_f32_16x16x32_bf16(pa1, v1, accO[dt], 0, 0, 0);
        }
        __syncthreads();   // protect Ks/VTs before next stage
    }

    // epilogue: out[b][s][h*64+d] = O / l
#pragma unroll
    for (int dt = 0; dt < 4; ++dt) {
        int d = dt * 16 + lo;
#pragma unroll
        for (int r = 0; r < 4; ++r) {
            int row = q0 + w * 16 + g * 4 + r;
            out[((size_t)(b * S_ + row)) * H_ + h * HD_ + d] = accO[dt][r] / li[r];
        }
    }
}

extern "C" void kernel_launch(void* const* d_in, const int* in_sizes, int n_in,
                              void* d_out, int out_size, void* d_ws, size_t ws_size,
                              hipStream_t stream) {
    const float* hs   = (const float*)d_in[0];
    const float* mask = (const float*)d_in[1];
    const float* rel  = (const float*)d_in[2];
    const float* Wq   = (const float*)d_in[3];
    const float* bq   = (const float*)d_in[4];
    const float* Wk   = (const float*)d_in[5];
    const float* bk   = (const float*)d_in[6];
    const float* Wv   = (const float*)d_in[7];
    const float* bv   = (const float*)d_in[8];
    float* out = (float*)d_out;

    const size_t qkv_elems = (size_t)B_ * NH_ * S_ * HD_;  // 4,194,304
    bf16_t* qbuf = (bf16_t*)d_ws;
    bf16_t* kbuf = qbuf + qkv_elems;
    bf16_t* vbuf = kbuf + qkv_elems;

    qkv_gemm<<<dim3(64, 16, 3), 256, 0, stream>>>(hs, Wq, bq, Wk, bk, Wv, bv,
                                                  qbuf, kbuf, vbuf);
    attn<<<dim3(S_ / 64, NH_, B_), 256, 0, stream>>>(qbuf, kbuf, vbuf, mask, rel, out);
}